// Round 10
// baseline (482.355 us; speedup 1.0000x reference)
//
#include <hip/hip_runtime.h>
#include <cmath>

#define B_    16
#define S_    1024
#define D_    256
#define H_    8
#define DH_   32
#define DFF_  1024
#define PDIM_ 64
#define N_    (B_ * S_)      // 16384
#define E_    262144
#define ETOT_ (E_ + N_)      // 278528
#define EPS_  1e-5f

typedef __attribute__((ext_vector_type(8))) short bf16x8;
typedef __attribute__((ext_vector_type(8))) unsigned short u16x8;
typedef __attribute__((ext_vector_type(4))) float f32x4;

// split-qkv buffer layout (ushort units), each array 4194304 elements:
// Qh 0, Ql +QKV_LO, Kh QKV_SEC, Kl +LO, Vh 2*QKV_SEC, Vl +LO.
// Q,K per-panel [S][32]; V per-panel TRANSPOSED [32][S].
#define QKV_SEC 8388608
#define QKV_LO  4194304
// split-h layout for GAT: Hh at 0, Hl at 4194304 (ushort units)
#define H_LO    4194304

// ---------------- wave helpers ----------------
__device__ __forceinline__ float wave_sum(float v) {
#pragma unroll
  for (int m = 1; m < 64; m <<= 1) v += __shfl_xor(v, m, 64);
  return v;
}
__device__ __forceinline__ float wave_max(float v) {
#pragma unroll
  for (int m = 1; m < 64; m <<= 1) v = fmaxf(v, __shfl_xor(v, m, 64));
  return v;
}

// bf16 split helpers (RNE)
__device__ __forceinline__ unsigned short f2bf(float f) {
  unsigned int u = __float_as_uint(f);
  unsigned int r = u + 0x7fffu + ((u >> 16) & 1u);
  return (unsigned short)(r >> 16);
}
__device__ __forceinline__ float bf2f(unsigned short s) {
  return __uint_as_float(((unsigned int)s) << 16);
}
__device__ __forceinline__ void split4(float4 v, ushort4& hi, ushort4& lo) {
  unsigned short h;
  h = f2bf(v.x); hi.x = h; lo.x = f2bf(v.x - bf2f(h));
  h = f2bf(v.y); hi.y = h; lo.y = f2bf(v.y - bf2f(h));
  h = f2bf(v.z); hi.z = h; lo.z = f2bf(v.z - bf2f(h));
  h = f2bf(v.w); hi.w = h; lo.w = f2bf(v.w - bf2f(h));
}
__device__ __forceinline__ ushort4 hi4(float4 v) {
  ushort4 h;
  h.x = f2bf(v.x); h.y = f2bf(v.y); h.z = f2bf(v.z); h.w = f2bf(v.w);
  return h;
}

// ---------------- gamma/beta for both AdaLNs ----------------
__global__ __launch_bounds__(256) void gamma_beta_kernel(
    const float* __restrict__ pc,
    const float* __restrict__ g1w, const float* __restrict__ g1b,
    const float* __restrict__ b1w, const float* __restrict__ b1b,
    const float* __restrict__ g2w, const float* __restrict__ g2b,
    const float* __restrict__ b2w, const float* __restrict__ b2b,
    float* __restrict__ gamma1, float* __restrict__ beta1,
    float* __restrict__ gamma2, float* __restrict__ beta2) {
  int i = blockIdx.x * 256 + threadIdx.x;
  if (i >= B_ * D_) return;
  int b = i >> 8, d = i & 255;
  const float* p = pc + b * PDIM_;
  float s1 = 0.f, s2 = 0.f, s3 = 0.f, s4 = 0.f;
#pragma unroll 8
  for (int k = 0; k < PDIM_; ++k) {
    float pv = p[k];
    s1 += pv * g1w[d * PDIM_ + k];
    s2 += pv * b1w[d * PDIM_ + k];
    s3 += pv * g2w[d * PDIM_ + k];
    s4 += pv * b2w[d * PDIM_ + k];
  }
  gamma1[i] = s1 + g1b[d];
  beta1[i]  = s2 + b1b[d];
  gamma2[i] = s3 + g2b[d];
  beta2[i]  = s4 + b2b[d];
}

// ---------------- AdaLN (plain LN -> gamma*xhat+beta -> LN(w,b)) ----------------
__global__ __launch_bounds__(256) void adaln_kernel(
    const float* __restrict__ x, const float* __restrict__ gamma,
    const float* __restrict__ beta, const float* __restrict__ lnw,
    const float* __restrict__ lnb, float* __restrict__ out) {
  int wid = threadIdx.x >> 6, lane = threadIdx.x & 63;
  int r = blockIdx.x * 4 + wid;
  int b = r >> 10;
  const int c = lane << 2;
  float4 v = *(const float4*)&x[(size_t)r * D_ + c];
  float sum = wave_sum(v.x + v.y + v.z + v.w);
  float mu = sum * (1.f / D_);
  float d0 = v.x - mu, d1 = v.y - mu, d2 = v.z - mu, d3 = v.w - mu;
  float sq = wave_sum(d0 * d0 + d1 * d1 + d2 * d2 + d3 * d3);
  float rs = rsqrtf(sq * (1.f / D_) + EPS_);
  float4 g  = *(const float4*)&gamma[b * D_ + c];
  float4 be = *(const float4*)&beta[b * D_ + c];
  float a0 = g.x * (d0 * rs) + be.x;
  float a1 = g.y * (d1 * rs) + be.y;
  float a2 = g.z * (d2 * rs) + be.z;
  float a3 = g.w * (d3 * rs) + be.w;
  float sum2 = wave_sum(a0 + a1 + a2 + a3);
  float mu2 = sum2 * (1.f / D_);
  float e0 = a0 - mu2, e1 = a1 - mu2, e2 = a2 - mu2, e3 = a3 - mu2;
  float sq2 = wave_sum(e0 * e0 + e1 * e1 + e2 * e2 + e3 * e3);
  float rs2 = rsqrtf(sq2 * (1.f / D_) + EPS_);
  float4 w  = *(const float4*)&lnw[c];
  float4 bb = *(const float4*)&lnb[c];
  float4 o;
  o.x = e0 * rs2 * w.x + bb.x;
  o.y = e1 * rs2 * w.y + bb.y;
  o.z = e2 * rs2 * w.z + bb.z;
  o.w = e3 * rs2 * w.w + bb.w;
  *(float4*)&out[(size_t)r * D_ + c] = o;
}

// ---------------- split-bf16 MFMA GEMM: C[M,Nc] = A[M,K]@W[Nc,K]^T ----------------
// A split hi+lo (2 MFMAs); B hi only.
// EPI: 0 none, 1 exact GELU, 2 +R, 3 split-QKV writeout (V transposed), 4 split-h.
template <int EPI, int MS>
__global__ __launch_bounds__(256) void gemm_mfma_kernel(
    const float* __restrict__ A, const float* __restrict__ Wt,
    const float* __restrict__ bias, const float* __restrict__ R,
    float* __restrict__ C, int M, int Nc, int K) {
  __shared__ __align__(16) unsigned short Ah[MS * 32][40];
  __shared__ __align__(16) unsigned short Al[MS * 32][40];
  __shared__ __align__(16) unsigned short Bh[128][40];
  const int t = threadIdx.x;
  const int w = t >> 6, l = t & 63;
  const int lr = l & 15, lg = l >> 4;
  const int bm = blockIdx.y * (MS * 32), bn = blockIdx.x * 128;
  constexpr int SA = (MS == 4) ? 1 : 2;
  constexpr int NA = (MS == 4) ? 4 : 2;
  const int sra = t >> SA;
  const int ska = (t & ((1 << SA) - 1)) * (NA * 4);
  const int srb = t >> 1;
  const int skb = (t & 1) * 16;
  const float* Ap = A + (size_t)(bm + sra) * K + ska;
  const float* Bp = Wt + (size_t)(bn + srb) * K + skb;

  f32x4 acc[MS][4];
#pragma unroll
  for (int i = 0; i < MS; ++i)
#pragma unroll
    for (int j = 0; j < 4; ++j) acc[i][j] = (f32x4){0.f, 0.f, 0.f, 0.f};

  float4 ra[NA], rb[4];
#pragma unroll
  for (int c = 0; c < NA; ++c) ra[c] = *(const float4*)(Ap + c * 4);
#pragma unroll
  for (int c = 0; c < 4; ++c) rb[c] = *(const float4*)(Bp + c * 4);

  const int nk = K >> 5;
  for (int kt = 0; kt < nk; ++kt) {
    __syncthreads();
#pragma unroll
    for (int c = 0; c < NA; ++c) {
      ushort4 h4, l4;
      split4(ra[c], h4, l4);
      *(ushort4*)&Ah[sra][ska + c * 4] = h4;
      *(ushort4*)&Al[sra][ska + c * 4] = l4;
    }
#pragma unroll
    for (int c = 0; c < 4; ++c) {
      *(ushort4*)&Bh[srb][skb + c * 4] = hi4(rb[c]);
    }
    if (kt + 1 < nk) {
      Ap += 32;
      Bp += 32;
#pragma unroll
      for (int c = 0; c < NA; ++c) ra[c] = *(const float4*)(Ap + c * 4);
#pragma unroll
      for (int c = 0; c < 4; ++c) rb[c] = *(const float4*)(Bp + c * 4);
    }
    __syncthreads();
    bf16x8 bhj[4];
#pragma unroll
    for (int j = 0; j < 4; ++j) {
      bhj[j] = *(const bf16x8*)&Bh[(w & 1) * 64 + j * 16 + lr][lg * 8];
    }
#pragma unroll
    for (int i = 0; i < MS; ++i) {
      bf16x8 ahi = *(const bf16x8*)&Ah[(w >> 1) * (MS * 16) + i * 16 + lr][lg * 8];
      bf16x8 ali = *(const bf16x8*)&Al[(w >> 1) * (MS * 16) + i * 16 + lr][lg * 8];
#pragma unroll
      for (int j = 0; j < 4; ++j) {
        acc[i][j] = __builtin_amdgcn_mfma_f32_16x16x32_bf16(ahi, bhj[j], acc[i][j], 0, 0, 0);
        acc[i][j] = __builtin_amdgcn_mfma_f32_16x16x32_bf16(ali, bhj[j], acc[i][j], 0, 0, 0);
      }
    }
  }
  // epilogue: m = bm + (w>>1)*MS*16 + i*16 + lg*4 + r ; n = bn + (w&1)*64 + j*16 + lr
#pragma unroll
  for (int i = 0; i < MS; ++i) {
    const int m0 = bm + (w >> 1) * (MS * 16) + i * 16 + lg * 4;
#pragma unroll
    for (int j = 0; j < 4; ++j) {
      const int n = bn + (w & 1) * 64 + j * 16 + lr;
      const float bv = bias ? bias[n] : 0.f;
#pragma unroll
      for (int r = 0; r < 4; ++r) {
        const int m = m0 + r;
        float v = acc[i][j][r] + bv;
        if constexpr (EPI == 3) {
          // split-QKV writeout: Q scaled by log2(e)/sqrt(32); V transposed
          const int sec = n >> 8, f = n & 255, hh = f >> 5, dd = f & 31;
          if (sec == 0) v *= 0.2550332772677823f;
          unsigned short hi = f2bf(v);
          unsigned short lo = f2bf(v - bf2f(hi));
          unsigned short* qs = (unsigned short*)C + (size_t)sec * QKV_SEC;
          size_t base;
          if (sec == 2) {
            base = ((size_t)((m >> 10) * H_ + hh) * 32 + dd) * S_ + (m & 1023);
          } else {
            base = ((size_t)((m >> 10) * H_ + hh) * S_ + (m & 1023)) * 32 + dd;
          }
          qs[base] = hi;
          qs[base + QKV_LO] = lo;
        } else if constexpr (EPI == 4) {
          unsigned short hi = f2bf(v);
          unsigned short lo = f2bf(v - bf2f(hi));
          unsigned short* hs = (unsigned short*)C;
          const size_t base = (size_t)m * D_ + n;
          hs[base] = hi;
          hs[base + H_LO] = lo;
        } else {
          const size_t idx = (size_t)m * Nc + n;
          if constexpr (EPI == 1) v = 0.5f * v * (1.f + erff(v * 0.7071067811865476f));
          if constexpr (EPI == 2) v += R[idx];
          C[idx] = v;
        }
      }
    }
  }
}

// ---------------- split-bf16 MFMA flash attention (pre-split, V pre-transposed) ----------------
// 1D grid 1024, XCD-swizzled: one (b,h) panel's 8 q-chunks land on ONE XCD.
// Block = 4 waves; 128 q-rows/block (32/wave, 2 subtiles of 16).
__global__ __launch_bounds__(256) void attn_kernel(
    const unsigned short* __restrict__ qkvs, float* __restrict__ ao) {
  __shared__ __align__(16) unsigned short KhL[64][40];
  __shared__ __align__(16) unsigned short KlL[64][40];
  __shared__ __align__(16) unsigned short VThL[32][66];
  __shared__ __align__(16) unsigned short VTlL[32][66];
  __shared__ __align__(16) unsigned short PhL[4][16][74];
  __shared__ __align__(16) unsigned short PlL[4][16][74];

  const int t = threadIdx.x;
  const int w = t >> 6;
  const int l = t & 63;
  const int lq = l & 15;
  const int g = l >> 4;
  // XCD-aware decode: panel = (idx>>3)*8 + (bid&7); q-chunk = idx&7
  const int bid = blockIdx.x;
  const int xcd = bid & 7, idx = bid >> 3;
  const int qt = idx & 7;
  const int pan = (idx >> 3) * 8 + xcd;  // 0..127 = b*8 + h
  const int h = pan & 7, b = pan >> 3;
  const int qbase = qt * 128 + w * 32;
  const size_t panel = (size_t)(b * H_ + h) * S_;    // Q/K row base [S][32]
  const size_t panelT = (size_t)(b * H_ + h) * 32;   // V^T row base [32][S]

  const unsigned short* Qh_g = qkvs;
  const unsigned short* Ql_g = qkvs + QKV_LO;
  const unsigned short* Kh_g = qkvs + QKV_SEC;
  const unsigned short* Kl_g = qkvs + QKV_SEC + QKV_LO;
  const unsigned short* Vh_g = qkvs + 2 * QKV_SEC;
  const unsigned short* Vl_g = qkvs + 2 * QKV_SEC + QKV_LO;

  bf16x8 qh[2], ql[2];
#pragma unroll
  for (int qs = 0; qs < 2; ++qs) {
    const size_t qi = (panel + qbase + qs * 16 + lq) * 32 + g * 8;
    qh[qs] = *(const bf16x8*)&Qh_g[qi];
    ql[qs] = *(const bf16x8*)&Ql_g[qi];
  }

  f32x4 oacc[2][2];
  float mrun[2], lrun[2];
#pragma unroll
  for (int qs = 0; qs < 2; ++qs) {
    oacc[qs][0] = (f32x4){0.f, 0.f, 0.f, 0.f};
    oacc[qs][1] = (f32x4){0.f, 0.f, 0.f, 0.f};
    mrun[qs] = -1e30f;
    lrun[qs] = 0.f;
  }

  const int key_s = t >> 2;   // K staging: key 0..63
  const int dg = t & 3;       // K staging: dim group of 8
  const int vr = t >> 3;      // V staging: dim 0..31
  const int vc = (t & 7) * 8; // V staging: key chunk

  for (int kt = 0; kt < 16; ++kt) {
    __syncthreads();
    // ---- stage K rows + V^T rows (both linear copies) ----
    {
      const size_t kb = (panel + kt * 64 + key_s) * 32 + dg * 8;
      *(u16x8*)&KhL[key_s][dg * 8] = *(const u16x8*)&Kh_g[kb];
      *(u16x8*)&KlL[key_s][dg * 8] = *(const u16x8*)&Kl_g[kb];
      const size_t vb = (panelT + vr) * S_ + kt * 64 + vc;
      *(u16x8*)&VThL[vr][vc] = *(const u16x8*)&Vh_g[vb];
      *(u16x8*)&VTlL[vr][vc] = *(const u16x8*)&Vl_g[vb];
    }
    __syncthreads();

    bf16x8 kfh[4], kfl[4];
#pragma unroll
    for (int i = 0; i < 4; ++i) {
      kfh[i] = *(const bf16x8*)&KhL[i * 16 + lq][g * 8];
      kfl[i] = *(const bf16x8*)&KlL[i * 16 + lq][g * 8];
    }

#pragma unroll
    for (int qs = 0; qs < 2; ++qs) {
      // ---- QK^T: S^T[key][q] ----
      f32x4 s[4];
#pragma unroll
      for (int i = 0; i < 4; ++i) {
        f32x4 c = (f32x4){0.f, 0.f, 0.f, 0.f};
        c = __builtin_amdgcn_mfma_f32_16x16x32_bf16(kfh[i], qh[qs], c, 0, 0, 0);
        c = __builtin_amdgcn_mfma_f32_16x16x32_bf16(kfh[i], ql[qs], c, 0, 0, 0);
        c = __builtin_amdgcn_mfma_f32_16x16x32_bf16(kfl[i], qh[qs], c, 0, 0, 0);
        s[i] = c;
      }
      // ---- online softmax with defer-max (THR=8, exp2 domain) ----
      float pm = -1e30f;
#pragma unroll
      for (int i = 0; i < 4; ++i)
#pragma unroll
        for (int r = 0; r < 4; ++r) pm = fmaxf(pm, s[i][r]);
      pm = fmaxf(pm, __shfl_xor(pm, 16, 64));
      pm = fmaxf(pm, __shfl_xor(pm, 32, 64));
      float rfac = 1.f;
      if (!__all(pm - mrun[qs] <= 8.f)) {
        float mnew = fmaxf(mrun[qs], pm);
        rfac = exp2f(mrun[qs] - mnew);
        mrun[qs] = mnew;
        oacc[qs][0] *= rfac;
        oacc[qs][1] *= rfac;
      }
      float lsum = 0.f;
#pragma unroll
      for (int i = 0; i < 4; ++i) {
        ushort4 hv, lv;
        unsigned short hr[4], lr4[4];
#pragma unroll
        for (int r = 0; r < 4; ++r) {
          float p = exp2f(s[i][r] - mrun[qs]);
          lsum += p;
          unsigned short ph = f2bf(p);
          hr[r] = ph;
          lr4[r] = f2bf(p - bf2f(ph));
        }
        hv.x = hr[0]; hv.y = hr[1]; hv.z = hr[2]; hv.w = hr[3];
        lv.x = lr4[0]; lv.y = lr4[1]; lv.z = lr4[2]; lv.w = lr4[3];
        *(ushort4*)&PhL[w][lq][i * 16 + g * 4] = hv;
        *(ushort4*)&PlL[w][lq][i * 16 + g * 4] = lv;
      }
      lsum += __shfl_xor(lsum, 16, 64);
      lsum += __shfl_xor(lsum, 32, 64);
      lrun[qs] = lrun[qs] * rfac + lsum;

      // ---- PV: O^T[dim][q] += V^T @ P^T ----
#pragma unroll
      for (int kh2 = 0; kh2 < 2; ++kh2) {
        bf16x8 pb = *(const bf16x8*)&PhL[w][lq][kh2 * 32 + g * 8];
        bf16x8 pl = *(const bf16x8*)&PlL[w][lq][kh2 * 32 + g * 8];
#pragma unroll
        for (int d = 0; d < 2; ++d) {
          bf16x8 vh = *(const bf16x8*)&VThL[d * 16 + lq][kh2 * 32 + g * 8];
          bf16x8 vl = *(const bf16x8*)&VTlL[d * 16 + lq][kh2 * 32 + g * 8];
          oacc[qs][d] = __builtin_amdgcn_mfma_f32_16x16x32_bf16(vh, pb, oacc[qs][d], 0, 0, 0);
          oacc[qs][d] = __builtin_amdgcn_mfma_f32_16x16x32_bf16(vh, pl, oacc[qs][d], 0, 0, 0);
          oacc[qs][d] = __builtin_amdgcn_mfma_f32_16x16x32_bf16(vl, pb, oacc[qs][d], 0, 0, 0);
        }
      }
    }
  }

  // ---- epilogue ----
#pragma unroll
  for (int qs = 0; qs < 2; ++qs) {
    float inv = 1.f / lrun[qs];
    const size_t orow =
        ((size_t)(b * S_ + qbase + qs * 16 + lq)) * D_ + h * DH_;
#pragma unroll
    for (int d = 0; d < 2; ++d) {
      float4 ov;
      ov.x = oacc[qs][d][0] * inv;
      ov.y = oacc[qs][d][1] * inv;
      ov.z = oacc[qs][d][2] * inv;
      ov.w = oacc[qs][d][3] * inv;
      *(float4*)&ao[orow + d * 16 + g * 4] = ov;
    }
  }
}

// ---------------- a_src/a_dst: per-node dots (split-bf16 h) ----------------
__global__ __launch_bounds__(256) void adot_kernel(
    const unsigned short* __restrict__ hs, const float* __restrict__ att_src,
    const float* __restrict__ att_dst, float* __restrict__ a_src,
    float* __restrict__ a_dst) {
  int wid = threadIdx.x >> 6, lane = threadIdx.x & 63;
  int n = blockIdx.x * 4 + wid;
  const int c = lane << 2;
  ushort4 hh = *(const ushort4*)&hs[(size_t)n * D_ + c];
  ushort4 hl = *(const ushort4*)&hs[H_LO + (size_t)n * D_ + c];
  float h0 = bf2f(hh.x) + bf2f(hl.x);
  float h1 = bf2f(hh.y) + bf2f(hl.y);
  float h2 = bf2f(hh.z) + bf2f(hl.z);
  float h3 = bf2f(hh.w) + bf2f(hl.w);
  float4 as = *(const float4*)&att_src[c];
  float4 ad = *(const float4*)&att_dst[c];
  float s = h0 * as.x + h1 * as.y + h2 * as.z + h3 * as.w;
  float d = h0 * ad.x + h1 * ad.y + h2 * ad.z + h3 * ad.w;
  s = wave_sum(s);
  d = wave_sum(d);
  if (lane == 0) { a_src[n] = s; a_dst[n] = d; }
}

// ---------------- GAT CSR build ----------------
__global__ __launch_bounds__(256) void hist_kernel(
    const int* __restrict__ e_dst, int* __restrict__ counts) {
  int i = blockIdx.x * 256 + threadIdx.x;
  if (i >= ETOT_) return;
  int dst = (i < E_) ? e_dst[i] : (i - E_);
  atomicAdd(&counts[dst], 1);
}

__global__ __launch_bounds__(1024) void scan_kernel(
    const int* __restrict__ counts, int* __restrict__ offsets,
    int* __restrict__ cursor) {
  __shared__ int sums[1024];
  const int t = threadIdx.x;
  int local[16];
  int s = 0;
#pragma unroll
  for (int i = 0; i < 16; ++i) { local[i] = s; s += counts[t * 16 + i]; }
  sums[t] = s;
  __syncthreads();
  for (int off = 1; off < 1024; off <<= 1) {
    int v = (t >= off) ? sums[t - off] : 0;
    __syncthreads();
    sums[t] += v;
    __syncthreads();
  }
  int base = (t > 0) ? sums[t - 1] : 0;
#pragma unroll
  for (int i = 0; i < 16; ++i) {
    int o = base + local[i];
    offsets[t * 16 + i] = o;
    cursor[t * 16 + i] = o;
  }
  if (t == 1023) offsets[N_] = sums[1023];
}

__global__ __launch_bounds__(256) void scatter_kernel(
    const int* __restrict__ e_src, const int* __restrict__ e_dst,
    int* __restrict__ cursor, int* __restrict__ csr_src) {
  int i = blockIdx.x * 256 + threadIdx.x;
  if (i >= ETOT_) return;
  int s = (i < E_) ? e_src[i] : (i - E_);
  int d = (i < E_) ? e_dst[i] : (i - E_);
  int slot = atomicAdd(&cursor[d], 1);
  csr_src[slot] = s;
}

// ---------------- GAT aggregate + bias + residual + gLN (one wave per node) ----------------
__global__ __launch_bounds__(256) void gat_ln_kernel(
    const unsigned short* __restrict__ hs, const float* __restrict__ a_src,
    const float* __restrict__ a_dst, const int* __restrict__ offsets,
    const int* __restrict__ csr_src, const float* __restrict__ gat_bias,
    const float* __restrict__ x1, const float* __restrict__ gln_w,
    const float* __restrict__ gln_b, float* __restrict__ x2) {
  int wid = threadIdx.x >> 6, lane = threadIdx.x & 63;
  int n = blockIdx.x * 4 + wid;
  const int c = lane << 2;
  int beg = offsets[n], end = offsets[n + 1];
  float adn = a_dst[n];
  float m = -1e30f;
  for (int j = beg + lane; j < end; j += 64) {
    float e = a_src[csr_src[j]] + adn;
    e = (e >= 0.f) ? e : 0.2f * e;
    m = fmaxf(m, e);
  }
  m = wave_max(m);
  float z = 0.f;
  float ac0 = 0.f, ac1 = 0.f, ac2 = 0.f, ac3 = 0.f;
  for (int j0 = beg; j0 < end; j0 += 64) {
    int j = j0 + lane;
    float wgt = 0.f;
    int sidx = 0;
    if (j < end) {
      sidx = csr_src[j];
      float e = a_src[sidx] + adn;
      e = (e >= 0.f) ? e : 0.2f * e;
      wgt = __expf(e - m);
    }
    z += wgt;
    int cnt = min(64, end - j0);
    for (int jj = 0; jj < cnt; ++jj) {
      float ww = __shfl(wgt, jj, 64);
      int ss = __shfl(sidx, jj, 64);
      ushort4 hv = *(const ushort4*)&hs[(size_t)ss * D_ + c];
      ac0 += ww * bf2f(hv.x);
      ac1 += ww * bf2f(hv.y);
      ac2 += ww * bf2f(hv.z);
      ac3 += ww * bf2f(hv.w);
    }
  }
  z = wave_sum(z);
  float inv = 1.f / z;
  float4 bv = *(const float4*)&gat_bias[c];
  float4 xv = *(const float4*)&x1[(size_t)n * D_ + c];
  float v0 = ac0 * inv + bv.x + xv.x;
  float v1 = ac1 * inv + bv.y + xv.y;
  float v2 = ac2 * inv + bv.z + xv.z;
  float v3 = ac3 * inv + bv.w + xv.w;
  float sum = wave_sum(v0 + v1 + v2 + v3);
  float mu = sum * (1.f / D_);
  float d0 = v0 - mu, d1 = v1 - mu, d2 = v2 - mu, d3 = v3 - mu;
  float sq = wave_sum(d0 * d0 + d1 * d1 + d2 * d2 + d3 * d3);
  float rs = rsqrtf(sq * (1.f / D_) + EPS_);
  float4 w4 = *(const float4*)&gln_w[c];
  float4 b4 = *(const float4*)&gln_b[c];
  float4 o;
  o.x = d0 * rs * w4.x + b4.x;
  o.y = d1 * rs * w4.y + b4.y;
  o.z = d2 * rs * w4.z + b4.z;
  o.w = d3 * rs * w4.w + b4.w;
  *(float4*)&x2[(size_t)n * D_ + c] = o;
}

// ---------------- launch ----------------
extern "C" void kernel_launch(void* const* d_in, const int* in_sizes, int n_in,
                              void* d_out, int out_size, void* d_ws,
                              size_t ws_size, hipStream_t stream) {
  const float* x         = (const float*)d_in[0];
  const float* prop_cond = (const float*)d_in[1];
  const int*   edges     = (const int*)d_in[2];
  const float* a1gw = (const float*)d_in[3];
  const float* a1gb = (const float*)d_in[4];
  const float* a1bw = (const float*)d_in[5];
  const float* a1bb = (const float*)d_in[6];
  const float* a2gw = (const float*)d_in[7];
  const float* a2gb = (const float*)d_in[8];
  const float* a2bw = (const float*)d_in[9];
  const float* a2bb = (const float*)d_in[10];
  const float* ln1w = (const float*)d_in[11];
  const float* ln1b = (const float*)d_in[12];
  const float* ln2w = (const float*)d_in[13];
  const float* ln2b = (const float*)d_in[14];
  const float* glnw = (const float*)d_in[15];
  const float* glnb = (const float*)d_in[16];
  const float* ipw  = (const float*)d_in[17];
  const float* ipb  = (const float*)d_in[18];
  const float* opw  = (const float*)d_in[19];
  const float* opb  = (const float*)d_in[20];
  const float* f1w  = (const float*)d_in[21];
  const float* f1b  = (const float*)d_in[22];
  const float* f2w  = (const float*)d_in[23];
  const float* f2b  = (const float*)d_in[24];
  const float* gatw = (const float*)d_in[25];
  const float* gats = (const float*)d_in[26];
  const float* gatd = (const float*)d_in[27];
  const float* gatb = (const float*)d_in[28];
  float* out = (float*)d_out;

  const int* e_src = edges;
  const int* e_dst = edges + E_;

  float* W = (float*)d_ws;
  const size_t F_BIG = 0;
  const size_t F_XN  = F_BIG + 16777216;
  const size_t F_X1  = F_XN + 4194304;
  const size_t F_H   = F_X1 + 4194304;
  const size_t F_X2  = F_H + 4194304;
  const size_t F_GB  = F_X2 + 4194304;
  const size_t F_AS  = F_GB + 16384;
  const size_t F_AD  = F_AS + N_;
  const size_t F_INT = F_AD + N_;
  float* buf_big = W + F_BIG;
  float* buf_xn  = W + F_XN;
  float* buf_x1  = W + F_X1;
  float* buf_h   = W + F_H;   // holds split-h (Hh, Hl) as ushort arrays
  float* buf_x2  = W + F_X2;
  float* gamma1  = W + F_GB;
  float* beta1   = gamma1 + 4096;
  float* gamma2  = beta1 + 4096;
  float* beta2   = gamma2 + 4096;
  float* a_src   = W + F_AS;
  float* a_dst   = W + F_AD;
  int* counts  = (int*)(W + F_INT);
  int* offsets = counts + N_;
  int* cursor  = offsets + N_ + 1;
  int* csr_src = cursor + N_;

  hipMemsetAsync(counts, 0, N_ * sizeof(int), stream);

  gamma_beta_kernel<<<16, 256, 0, stream>>>(prop_cond, a1gw, a1gb, a1bw, a1bb,
                                            a2gw, a2gb, a2bw, a2bb, gamma1,
                                            beta1, gamma2, beta2);
  adaln_kernel<<<N_ / 4, 256, 0, stream>>>(x, gamma1, beta1, ln1w, ln1b, buf_xn);
  // QKV projection + fused split/scale/transpose writeout (V transposed)
  gemm_mfma_kernel<3, 4><<<dim3(6, 128), 256, 0, stream>>>(
      buf_xn, ipw, ipb, nullptr, buf_big, N_, 768, 256);
  attn_kernel<<<1024, 256, 0, stream>>>(
      (const unsigned short*)buf_big, buf_xn);
  // out_proj + residual(x)
  gemm_mfma_kernel<2, 2><<<dim3(2, 256), 256, 0, stream>>>(
      buf_xn, opw, opb, x, buf_x1, N_, 256, 256);
  // GAT h = x1 @ gat_w^T  -> split-bf16 writeout
  gemm_mfma_kernel<4, 2><<<dim3(2, 256), 256, 0, stream>>>(
      buf_x1, gatw, nullptr, nullptr, buf_h, N_, 256, 256);
  adot_kernel<<<N_ / 4, 256, 0, stream>>>((const unsigned short*)buf_h, gats,
                                          gatd, a_src, a_dst);
  hist_kernel<<<(ETOT_ + 255) / 256, 256, 0, stream>>>(e_dst, counts);
  scan_kernel<<<1, 1024, 0, stream>>>(counts, offsets, cursor);
  scatter_kernel<<<(ETOT_ + 255) / 256, 256, 0, stream>>>(e_src, e_dst, cursor,
                                                          csr_src);
  gat_ln_kernel<<<N_ / 4, 256, 0, stream>>>((const unsigned short*)buf_h,
                                            a_src, a_dst, offsets, csr_src,
                                            gatb, buf_x1, glnw, glnb, buf_x2);
  adaln_kernel<<<N_ / 4, 256, 0, stream>>>(buf_x2, gamma2, beta2, ln2w, ln2b,
                                           buf_xn);
  // FFN1 + GELU
  gemm_mfma_kernel<1, 4><<<dim3(8, 128), 256, 0, stream>>>(
      buf_xn, f1w, f1b, nullptr, buf_big, N_, DFF_, 256);
  // FFN2 + residual(x2)
  gemm_mfma_kernel<2, 2><<<dim3(2, 256), 256, 0, stream>>>(
      buf_big, f2w, f2b, buf_x2, out, N_, 256, DFF_);
}